// Round 1
// baseline (84.223 us; speedup 1.0000x reference)
//
#include <hip/hip_runtime.h>

#define FEPS 1e-8f

// v_rcp_f32: 1-instruction ~1ulp reciprocal. rcp(+-0)=+-inf gives correct
// Liang-Barsky behavior for axis-parallel edges (slab -> no constraint or
// reject via empty [t0,t1]), so no parallel-edge guard is needed.
__device__ __forceinline__ float fastrcp(float x) {
    return __builtin_amdgcn_rcpf(x);
}

// Clip the segment P + t*D (t in [0,1]) against the axis-aligned slabs
// [-hw,hw] x [-hh,hh], where (a0,a1) = P in the slab frame and
// (inv0,inv1) = 1/D componentwise (precomputed; negation is free on use).
// Returns the surviving span length max(t1-t0, 0).
// NaN from 0*inf (edge exactly on a slab face) is dropped by IEEE
// minNum/maxNum semantics of v_min/v_max, yielding span 0 -- identical
// semantics to the previous verified kernel.
__device__ __forceinline__ float clip_span(
    float a0, float a1, float inv0, float inv1, float hw, float hh)
{
    float tA0 = ( hw - a0) * inv0;
    float tB0 = (-hw - a0) * inv0;
    float tA1 = ( hh - a1) * inv1;
    float tB1 = (-hh - a1) * inv1;
    float lo0 = fminf(tA0, tB0), hi0 = fmaxf(tA0, tB0);
    float lo1 = fminf(tA1, tB1), hi1 = fmaxf(tA1, tB1);
    float t0 = fmaxf(0.0f, fmaxf(lo0, lo1));   // v_max3
    float t1 = fminf(1.0f, fminf(hi0, hi1));   // v_min3
    return fmaxf(t1 - t0, 0.0f);
}

// Rotated-box IoU computed entirely in the two box frames.
// Key identities (exact algebra, hand-verified):
//  * shoelace piece of a clipped edge: cross(s,e) = (t1-t0)*cross(P,D)
//  * box2's own edges in its own frame: cross(P,D) = A2/2 (constant)
//  * box1's edges in box2's frame: cross(G_k,d_k) = A1/2 + cross(q,d_k),
//    with d_k in {-2e1,-2f1,+2e1,+2f1} -> only 2 distinct cross(q,.) values
//  * rcp(-x) = -rcp(x) -> 8 reciprocals for 8 edges (opposite edges share)
__device__ __forceinline__ float one_iou(
    float p0, float p1, float p2, float p3, float p4,
    float t0, float t1, float t2, float t3, float t4)
{
    const float DEG = 0.017453292519943295f;
    float aa1 = p4 * DEG;                        // deg2rad(pred angle)
    float aa2 = (t4 * 180.0f - 180.0f) * DEG;    // deg2rad(target*180-180)
    float s1 = __sinf(aa1), c1 = __cosf(aa1);
    float s2 = __sinf(aa2), c2 = __cosf(aa2);

    // box1 center in box2's frame, relative rotation w = a1 - a2
    float dx = p0 - t0, dy = p1 - t1;
    float qx =  dx * c2 + dy * s2;
    float qy = -dx * s2 + dy * c2;
    float cw = c1 * c2 + s1 * s2;                // cos(a1-a2)
    float sw = s1 * c2 - c1 * s2;                // sin(a1-a2)

    float hw1 = 0.5f * p2, hh1 = 0.5f * p3;
    float hw2 = 0.5f * t2, hh2 = 0.5f * t3;
    float area1 = p2 * p3, area2 = t2 * t3;

    // -------- pass 1: box1 edges clipped by box2 (frame2) --------
    // rotated half-edge vectors of box1 in frame2
    float e1x =  hw1 * cw, e1y = hw1 * sw;       // R(w)*(hw1,0)
    float f1x = -hh1 * sw, f1y = hh1 * cw;       // R(w)*(0,hh1)

    // corners G_k = q +-e1 +-f1, CCW order (+,+),(-,+),(-,-),(+,-)
    float qpex = qx + e1x, qpey = qy + e1y;
    float qmex = qx - e1x, qmey = qy - e1y;
    float G0x = qpex + f1x, G0y = qpey + f1y;
    float G1x = qmex + f1x, G1y = qmey + f1y;
    float G2x = qmex - f1x, G2y = qmey - f1y;
    float G3x = qpex - f1x, G3y = qpey - f1y;

    // edge dirs: d0=-2e1, d1=-2f1, d2=+2e1, d3=+2f1 -> 4 reciprocals
    float i_ex = fastrcp(-2.0f * e1x), i_ey = fastrcp(-2.0f * e1y);
    float i_fx = fastrcp(-2.0f * f1x), i_fy = fastrcp(-2.0f * f1y);

    // shoelace weights w_k = A1/2 + cross(q, d_k)
    float halfA1 = 0.5f * area1;
    float X2 = 2.0f * (qx * e1y - qy * e1x);     // cross(q, 2*e1)
    float Y2 = 2.0f * (qx * f1y - qy * f1x);     // cross(q, 2*f1)
    float w0 = halfA1 - X2;
    float w1 = halfA1 - Y2;
    float w2 = halfA1 + X2;
    float w3 = halfA1 + Y2;

    float sum = 0.0f;
    sum += clip_span(G0x, G0y,  i_ex,  i_ey, hw2, hh2) * w0;
    sum += clip_span(G1x, G1y,  i_fx,  i_fy, hw2, hh2) * w1;
    sum += clip_span(G2x, G2y, -i_ex, -i_ey, hw2, hh2) * w2;
    sum += clip_span(G3x, G3y, -i_fx, -i_fy, hw2, hh2) * w3;

    // -------- pass 2: box2 edges clipped by box1 (frame1) --------
    // box2 corners in box1's frame: Hf_k = m +-e2 +-f2
    float e2x = hw2 * cw, e2y = -hw2 * sw;       // R(-w)*(hw2,0)
    float f2x = hh2 * sw, f2y =  hh2 * cw;       // R(-w)*(0,hh2)
    float mx = -(qx * cw + qy * sw);             // R(-w)*(-q)
    float my =   qx * sw - qy * cw;
    float mpex = mx + e2x, mpey = my + e2y;
    float mmex = mx - e2x, mmey = my - e2y;
    float H0x = mpex + f2x, H0y = mpey + f2y;
    float H1x = mmex + f2x, H1y = mmey + f2y;
    float H2x = mmex - f2x, H2y = mmey - f2y;
    float H3x = mpex - f2x, H3y = mpey - f2y;

    float j_ex = fastrcp(-2.0f * e2x), j_ey = fastrcp(-2.0f * e2y);
    float j_fx = fastrcp(-2.0f * f2x), j_fy = fastrcp(-2.0f * f2y);

    // all 4 shoelace weights equal A2/2 (box2 centered in its own frame)
    float span = 0.0f;
    span += clip_span(H0x, H0y,  j_ex,  j_ey, hw1, hh1);
    span += clip_span(H1x, H1y,  j_fx,  j_fy, hw1, hh1);
    span += clip_span(H2x, H2y, -j_ex, -j_ey, hw1, hh1);
    span += clip_span(H3x, H3y, -j_fx, -j_fy, hw1, hh1);
    sum += span * (0.5f * area2);

    float inter = 0.5f * fabsf(sum);
    float uni = area1 + area2 - inter;
    float iou = inter * fastrcp(uni + FEPS);
    return fminf(fmaxf(iou, 1e-7f), 1.0f - 1e-7f);
}

// One box per thread; per-block partial STORED (not atomic) to its own slot.
// Every slot written every launch -> no init, no memset, and no same-line
// atomic chain (prior session: a single ticket line cost ~90us at 3072 blocks).
__global__ __launch_bounds__(256) void riou_kernel(
    const float* __restrict__ pred, const float* __restrict__ target,
    const int* __restrict__ pos_idx, float* __restrict__ out,
    float2* __restrict__ partials, int n)
{
    int gid = blockIdx.x * blockDim.x + threadIdx.x;
    float lnum = 0.0f, lden = 0.0f;

    if (gid < n) {
        const float* p = pred + (size_t)gid * 5;
        const float* t = target + (size_t)gid * 5;
        float iou = one_iou(p[0], p[1], p[2], p[3], p[4],
                            t[0], t[1], t[2], t[3], t[4]);
        out[1 + gid] = iou;
        float m = (pos_idx[gid] != 0) ? 1.0f : 0.0f;
        lnum = (1.0f - iou) * m;
        lden = m;
    }

    #pragma unroll
    for (int off = 32; off > 0; off >>= 1) {
        lnum += __shfl_down(lnum, off);
        lden += __shfl_down(lden, off);
    }
    __shared__ float snum[4], sden[4];
    int wave = threadIdx.x >> 6, lane = threadIdx.x & 63;
    if (lane == 0) { snum[wave] = lnum; sden[wave] = lden; }
    __syncthreads();
    if (threadIdx.x == 0) {
        float bn = snum[0] + snum[1] + snum[2] + snum[3];
        float bd = sden[0] + sden[1] + sden[2] + sden[3];
        partials[blockIdx.x] = make_float2(bn, bd);
    }
}

__global__ __launch_bounds__(1024) void riou_finalize(
    const float2* __restrict__ partials, int nb, float* __restrict__ out)
{
    double num = 0.0, den = 0.0;
    for (int i = threadIdx.x; i < nb; i += 1024) {   // 3 iters at nb=3072
        float2 p = partials[i];
        num += (double)p.x;
        den += (double)p.y;
    }
    #pragma unroll
    for (int off = 32; off > 0; off >>= 1) {
        num += __shfl_down(num, off);
        den += __shfl_down(den, off);
    }
    __shared__ double dn[16], dd[16];
    int wave = threadIdx.x >> 6, lane = threadIdx.x & 63;
    if (lane == 0) { dn[wave] = num; dd[wave] = den; }
    __syncthreads();
    if (threadIdx.x == 0) {
        double n2 = 0.0, d2 = 0.0;
        #pragma unroll
        for (int w = 0; w < 16; ++w) { n2 += dn[w]; d2 += dd[w]; }
        out[0] = (float)(n2 / fmax(d2, 1.0));
    }
}

extern "C" void kernel_launch(void* const* d_in, const int* in_sizes, int n_in,
                              void* d_out, int out_size, void* d_ws, size_t ws_size,
                              hipStream_t stream) {
    const float* pred   = (const float*)d_in[0];
    const float* target = (const float*)d_in[1];
    const int*   posidx = (const int*)d_in[2];
    float* out = (float*)d_out;

    int n = in_sizes[0] / 5;
    int block = 256;
    int grid = (n + block - 1) / block;
    float2* partials = (float2*)d_ws;

    riou_kernel<<<grid, block, 0, stream>>>(pred, target, posidx, out,
                                            partials, n);
    riou_finalize<<<1, 1024, 0, stream>>>(partials, grid, out);
}